// Round 19
// baseline (1042.105 us; speedup 1.0000x reference)
//
#include <hip/hip_runtime.h>
#include <hip/hip_bf16.h>
#include <math.h>

#define PP 196608
#define NK 8

#define O_SIGALL 589824
#define O_RGB    786432
#define O_SIG    5505024

typedef __attribute__((ext_vector_type(8))) short short8;
typedef __attribute__((ext_vector_type(4))) float f32x4;
typedef __attribute__((ext_vector_type(4))) unsigned uint4v;

// ---- f32 table offsets (floats; bytes 0..6143 of ws and LDS) ----
#define FBB0   0
#define FBA0   512
#define FBB1   1024
#define FBB2   1088
#define FBA1   1152
#define FBA2   1216
#define FBL    1280
#define FBV    1344
#define FBC0   1376
#define FBC1   1392
#define FW32B0 1408
#define FW32A0 1472
// f32 total = 1536 floats = 6144 bytes

// ---- bf16 fragment regions (shorts; 1 frag = 64 lanes x 8 shorts = 512) ----
#define FB0 0
#define FB1 2048
#define FB2 6144
#define FA0 10240
#define FA1 16384
#define FA2 20480
#define FL  24576
#define FV  28672
#define FC0 31744
#define FC1 32256
// frag total = 32768 shorts = 65536 bytes; image = 71680 bytes

#define WS_BYTES 71680

__device__ __forceinline__ short bfr(float f) {
    unsigned u = __builtin_bit_cast(unsigned, f);
    unsigned r = (u + 0x7FFFu + ((u >> 16) & 1u)) >> 16;
    return (short)r;
}

// packed pair f32 -> 2x bf16 (RNE) in one u32
__device__ __forceinline__ unsigned pk2(float a, float b) {
    __hip_bfloat162 h = __float22bfloat162_rn(float2{a, b});
    unsigned r;
    __builtin_memcpy(&r, &h, sizeof(r));
    return r;
}

__device__ __forceinline__ int tau(int p) {
    return 16 * ((p >> 2) & 1) + 4 * (p >> 3) + (p & 3);
}

__device__ __forceinline__ float pe_elem(int j, float c0, float c1, float c2, int jmax) {
    int r = j - 3;
    int rf = r < 0 ? 0 : r;
    int f = rf / 6;
    int t = rf - 6 * f;
    int comp = (j < 3) ? j : (t >= 3 ? t - 3 : t);
    float c = (comp == 0) ? c0 : ((comp == 1) ? c1 : c2);
    float x = c * (float)(1 << f);
    float val = (t < 3) ? sinf(x) : cosf(x);
    if (j < 3) val = c;
    return (j < jmax) ? val : 0.f;
}

// fast softplus: hardware exp/log (v_exp_f32 / v_log_f32), ~1e-6 rel err
__device__ __forceinline__ float softplus_(float d) {
    return fmaxf(d, 0.f) + __logf(1.f + __expf(-fabsf(d)));
}
// (tanh(x)+1)/2 == sigmoid(2x); 4 VALU via v_exp
__device__ __forceinline__ float half_tanh1(float x) {
    return 1.f / (1.f + __expf(-2.f * x));
}

#define MFMA(a, b, c) __builtin_amdgcn_mfma_f32_16x16x32_bf16(a, b, c, 0, 0, 0)

// ================= prep kernel: frag-linear ws image (verified) =================
__global__ void prep_kernel(
    const float* __restrict__ slots,
    const float* __restrict__ Wb0, const float* __restrict__ bb0,
    const float* __restrict__ Wb1, const float* __restrict__ bb1,
    const float* __restrict__ Wb2, const float* __restrict__ bb2,
    const float* __restrict__ Wa0, const float* __restrict__ ba0,
    const float* __restrict__ Wa1, const float* __restrict__ ba1,
    const float* __restrict__ Wa2, const float* __restrict__ ba2,
    const float* __restrict__ Wl,  const float* __restrict__ bl,
    const float* __restrict__ Wv,  const float* __restrict__ bv,
    const float* __restrict__ Wc0, const float* __restrict__ bc0,
    const float* __restrict__ Wc1, const float* __restrict__ bc1,
    char* __restrict__ ws)
{
    float* wsF = (float*)ws;
    short* wsS = (short*)(ws + 6144);
    const int tid = threadIdx.x;

    for (int idx = tid; idx < 512; idx += 256) {
        int k = idx >> 6, j = idx & 63;
        const float* sl = slots + k * 64;
        float a = bb0[j];
        const float* w0 = Wb0 + j * 97 + 33;
        for (int i = 0; i < 64; ++i) a = fmaf(w0[i], sl[i], a);
        wsF[FBB0 + idx] = a;
        float b = ba0[j];
        const float* w1 = Wa0 + j * 161 + 33;
        for (int i = 0; i < 64; ++i) b = fmaf(w1[i], sl[i], b);
        wsF[FBA0 + idx] = b;
    }
    for (int idx = tid; idx < 64; idx += 256) {
        wsF[FBB1 + idx] = bb1[idx];
        wsF[FBB2 + idx] = bb2[idx];
        wsF[FBA1 + idx] = ba1[idx];
        wsF[FBA2 + idx] = ba2[idx];
        wsF[FBL  + idx] = bl[idx];
        wsF[FW32B0 + idx] = Wb0[idx * 97 + 32];
        wsF[FW32A0 + idx] = Wa0[idx * 161 + 32];
        if (idx < 32) wsF[FBV + idx] = bv[idx];
        if (idx < 16) { wsF[FBC0 + idx] = bc0[idx];
                        wsF[FBC1 + idx] = (idx < 3) ? bc1[idx] : 0.f; }
    }
    for (int idx = tid; idx < 2048; idx += 256) {
        int frag = idx >> 9, rem = idx & 511, L = rem >> 3, i = rem & 7;
        int r = 16 * frag + (L & 15);
        int cif = 8 * (L >> 4) + i;
        wsS[FB0 + idx] = bfr(Wb0[r * 97 + tau(cif)]);
    }
#define PREP64(FOFF, W) \
    for (int idx = tid; idx < 4096; idx += 256) { \
        int frag = idx >> 9, rem = idx & 511, L = rem >> 3, i = rem & 7; \
        int t = frag >> 1, s = frag & 1; \
        int r = 16 * t + (L & 15); \
        int cif = 8 * (L >> 4) + i; \
        int C = 32 * s + cif; \
        int lc = (C & ~31) + tau(C & 31); \
        wsS[(FOFF) + idx] = bfr(W[r * 64 + lc]); }
    PREP64(FB1, Wb1)
    PREP64(FB2, Wb2)
    PREP64(FA1, Wa1)
    PREP64(FA2, Wa2)
    PREP64(FL,  Wl)
#undef PREP64
    for (int idx = tid; idx < 6144; idx += 256) {
        int frag = idx >> 9, rem = idx & 511, L = rem >> 3, i = rem & 7;
        int t = frag / 3, s = frag % 3;
        int r = 16 * t + (L & 15);
        int cif = 8 * (L >> 4) + i;
        float v;
        if (s == 0) v = Wa0[r * 161 + tau(cif)];
        else {
            int lc = (s == 1 ? 64 : 96) + tau(cif);
            v = Wa0[r * 161 + 33 + lc];
        }
        wsS[FA0 + idx] = bfr(v);
    }
    for (int idx = tid; idx < 3072; idx += 256) {
        int frag = idx >> 9, rem = idx & 511, L = rem >> 3, i = rem & 7;
        int t = frag / 3, s = frag % 3;
        int r = 16 * t + (L & 15);
        int cif = 8 * (L >> 4) + i;
        int C = 32 * s + cif;
        int lc = (C & ~31) + tau(C & 31);
        wsS[FV + idx] = bfr(lc < 85 ? Wv[r * 85 + lc] : 0.f);
    }
    for (int idx = tid; idx < 512; idx += 256) {
        int L = idx >> 3, i = idx & 7;
        int r = L & 15;
        int cif = 8 * (L >> 4) + i;
        int lc = tau(cif);
        wsS[FC0 + idx] = bfr(Wc0[r * 32 + lc]);
        wsS[FC1 + idx] = bfr((r < 3 && lc < 16) ? Wc1[r * 16 + lc] : 0.f);
    }
}

// ---- LDS access (lane-linear frags: conflict-free ds_read_b128; verified) ----
#define FRAG(base, f) (*(const short8*)(shS + (base) + (f) * 512 + l * 8))
#define BIA(off, t)   (*(const f32x4*)(shF + (off) + 16 * (t) + g4))
#define BSLOT(off, kidx, t) (*(const f32x4*)(shF + (off) + (kidx) * 64 + 16 * (t) + g4))

#define PACKP(cA, cB, dst) { uint4v u_; \
  u_[0] = pk2(fmaxf((cA)[0],0.f), fmaxf((cA)[1],0.f)); \
  u_[1] = pk2(fmaxf((cA)[2],0.f), fmaxf((cA)[3],0.f)); \
  u_[2] = pk2(fmaxf((cB)[0],0.f), fmaxf((cB)[1],0.f)); \
  u_[3] = pk2(fmaxf((cB)[2],0.f), fmaxf((cB)[3],0.f)); \
  dst = __builtin_bit_cast(short8, u_); }

#define PACKN(cA, cB, dst) { uint4v u_; \
  u_[0] = pk2((cA)[0], (cA)[1]); \
  u_[1] = pk2((cA)[2], (cA)[3]); \
  u_[2] = pk2((cB)[0], (cB)[1]); \
  u_[3] = pk2((cB)[2], (cB)[3]); \
  dst = __builtin_bit_cast(short8, u_); }

#define ADD32(c, wv) { (c)[0]=fmaf((wv)[0],cosv,(c)[0]); (c)[1]=fmaf((wv)[1],cosv,(c)[1]); \
                       (c)[2]=fmaf((wv)[2],cosv,(c)[2]); (c)[3]=fmaf((wv)[3],cosv,(c)[3]); }

// 64x64 layer for SLOT PAIR: one frag-read set serves both slots.
#define LAYER64_2(FB, BOFF, PK) { \
  short8 A00=FRAG(FB,0), A01=FRAG(FB,1), A10=FRAG(FB,2), A11=FRAG(FB,3); \
  short8 A20=FRAG(FB,4), A21=FRAG(FB,5), A30=FRAG(FB,6), A31=FRAG(FB,7); \
  f32x4 b0_=BIA(BOFF,0), b1_=BIA(BOFF,1), b2_=BIA(BOFF,2), b3_=BIA(BOFF,3); \
  f32x4 c0=b0_, c1=b1_, c2=b2_, c3=b3_; \
  c0=MFMA(A00,p0a,c0); c1=MFMA(A10,p0a,c1); c2=MFMA(A20,p0a,c2); c3=MFMA(A30,p0a,c3); \
  c0=MFMA(A01,p1a,c0); c1=MFMA(A11,p1a,c1); c2=MFMA(A21,p1a,c2); c3=MFMA(A31,p1a,c3); \
  PK(c0,c1,p0a); PK(c2,c3,p1a); \
  f32x4 d0=b0_, d1=b1_, d2=b2_, d3=b3_; \
  d0=MFMA(A00,p0b,d0); d1=MFMA(A10,p0b,d1); d2=MFMA(A20,p0b,d2); d3=MFMA(A30,p0b,d3); \
  d0=MFMA(A01,p1b,d0); d1=MFMA(A11,p1b,d1); d2=MFMA(A21,p1b,d2); d3=MFMA(A31,p1b,d3); \
  PK(d0,d1,p0b); PK(d2,d3,p1b); }

// tail for one slot (AV*/AC* frags shared, loaded by caller)
#define TAIL1(PA, PB, KIDX) { \
  f32x4 cv0 = BIA(FBV, 0), cv1 = BIA(FBV, 1); \
  cv0 = MFMA(AV00, PA, cv0); cv1 = MFMA(AV10, PA, cv1); \
  cv0 = MFMA(AV01, PB, cv0); cv1 = MFMA(AV11, PB, cv1); \
  cv0 = MFMA(AV02, vembB, cv0); cv1 = MFMA(AV12, vembB, cv1); \
  short8 vB; PACKP(cv0, cv1, vB); \
  f32x4 cc = BIA(FBC0, 0); \
  cc = MFMA(AC0f, vB, cc); \
  short8 cB; \
  { uint4v u_; \
    u_[0] = pk2(fmaxf(cc[0],0.f), fmaxf(cc[1],0.f)); \
    u_[1] = pk2(fmaxf(cc[2],0.f), fmaxf(cc[3],0.f)); \
    u_[2] = 0u; u_[3] = 0u; \
    cB = __builtin_bit_cast(short8, u_); } \
  f32x4 cf = BIA(FBC1, 0); \
  cf = MFMA(AC1f, cB, cf); \
  if (l < 16) { \
      int base_ = O_RGB + ((KIDX) * PP + p) * 3; \
      out[base_ + 0] = half_tanh1(cf[0]); \
      out[base_ + 1] = half_tanh1(cf[1]); \
      out[base_ + 2] = half_tanh1(cf[2]); } }

// ================= pass A: 128 points/block (8 waves), 2 slots per iter =================
__global__ __launch_bounds__(512, 4) void decoder_kernel(
    const float* __restrict__ coor,
    const float* __restrict__ view,
    const float* __restrict__ dens,
    const float* __restrict__ act_shift,
    const int*   __restrict__ ray_id,
    const char*  __restrict__ ws,
    float* __restrict__ out)
{
    __shared__ __align__(16) char sh[WS_BYTES];
    const float* shF = (const float*)sh;
    const short* shS = (const short*)(sh + 6144);

    const int tid = threadIdx.x;
    const int l   = tid & 63;
    const int l15 = l & 15;
    const int g   = (l >> 4) & 3;
    const int g4  = g * 4;
    const int p   = blockIdx.x * 128 + (tid >> 6) * 16 + l15;

    // ---- stage weight image into LDS (one coalesced pass) ----
    {
        f32x4* dst = (f32x4*)sh;
        const f32x4* src = (const f32x4*)ws;
        for (int i = tid; i < WS_BYTES / 16; i += 512) dst[i] = src[i];
    }

    // ---- pos-emb fragment + col-32 scalar: ONCE per point ----
    short8 embB0;
    float cosv;
    {
        float c0 = coor[p * 3 + 0], c1 = coor[p * 3 + 1], c2 = coor[p * 3 + 2];
        #pragma unroll
        for (int i = 0; i < 8; ++i) {
            int j = ((i >> 2) * 16) + 4 * g + (i & 3);
            embB0[i] = bfr(pe_elem(j, c0, c1, c2, 33));
        }
        cosv = cosf(c2 * 16.f);
    }
    // ---- view embedding fragment: ONCE per point ----
    short8 vembB;
    {
        int rid = ray_id[p];
        float v0 = view[rid * 3 + 0], v1 = view[rid * 3 + 1], v2 = view[rid * 3 + 2];
        #pragma unroll
        for (int i = 0; i < 8; ++i) {
            int j = ((i >> 2) * 16) + 4 * g + (i & 3);
            vembB[i] = bfr(pe_elem(j, v0, v1, v2, 21));
        }
    }
    float shift = act_shift[0];

    __syncthreads();   // LDS image ready

    #pragma unroll 1
    for (int kk = 0; kk < 4; ++kk) {
        const int k0 = 2 * kk, k1 = 2 * kk + 1;

        { // both slots' sigma
            float da = dens[k0 * PP + p] + shift;
            float sa = softplus_(da);
            if (l < 16) out[O_SIG + k0 * PP + p] = sa;
            float db = dens[k1 * PP + p] + shift;
            float sb = softplus_(db);
            if (l < 16) out[O_SIG + k1 * PP + p] = sb;
        }

        short8 p0a, p1a, p0b, p1b;

        { // b0: shared W*emb + col32, per-slot bias add
            short8 A0 = FRAG(FB0, 0), A1 = FRAG(FB0, 1), A2 = FRAG(FB0, 2), A3 = FRAG(FB0, 3);
            f32x4 wv0 = BIA(FW32B0, 0), wv1 = BIA(FW32B0, 1), wv2 = BIA(FW32B0, 2), wv3 = BIA(FW32B0, 3);
            f32x4 z = {0.f, 0.f, 0.f, 0.f};
            f32x4 t0 = MFMA(A0, embB0, z), t1 = MFMA(A1, embB0, z);
            f32x4 t2 = MFMA(A2, embB0, z), t3 = MFMA(A3, embB0, z);
            ADD32(t0, wv0) ADD32(t1, wv1) ADD32(t2, wv2) ADD32(t3, wv3)
            f32x4 c0 = t0 + BSLOT(FBB0, k0, 0), c1 = t1 + BSLOT(FBB0, k0, 1);
            f32x4 c2 = t2 + BSLOT(FBB0, k0, 2), c3 = t3 + BSLOT(FBB0, k0, 3);
            PACKP(c0, c1, p0a); PACKP(c2, c3, p1a);
            f32x4 d0 = t0 + BSLOT(FBB0, k1, 0), d1 = t1 + BSLOT(FBB0, k1, 1);
            f32x4 d2 = t2 + BSLOT(FBB0, k1, 2), d3 = t3 + BSLOT(FBB0, k1, 3);
            PACKP(d0, d1, p0b); PACKP(d2, d3, p1b);
        }
        LAYER64_2(FB1, FBB1, PACKP)
        LAYER64_2(FB2, FBB2, PACKP)
        { // a0: shared W_emb*emb + col32; per-slot bias + skip MFMAs
            short8 E0 = FRAG(FA0, 0), K00 = FRAG(FA0, 1),  K01 = FRAG(FA0, 2);
            short8 E1 = FRAG(FA0, 3), K10 = FRAG(FA0, 4),  K11 = FRAG(FA0, 5);
            short8 E2 = FRAG(FA0, 6), K20 = FRAG(FA0, 7),  K21 = FRAG(FA0, 8);
            short8 E3 = FRAG(FA0, 9), K30 = FRAG(FA0, 10), K31 = FRAG(FA0, 11);
            f32x4 wv0 = BIA(FW32A0, 0), wv1 = BIA(FW32A0, 1), wv2 = BIA(FW32A0, 2), wv3 = BIA(FW32A0, 3);
            f32x4 z = {0.f, 0.f, 0.f, 0.f};
            f32x4 s0 = MFMA(E0, embB0, z), s1 = MFMA(E1, embB0, z);
            f32x4 s2 = MFMA(E2, embB0, z), s3 = MFMA(E3, embB0, z);
            ADD32(s0, wv0) ADD32(s1, wv1) ADD32(s2, wv2) ADD32(s3, wv3)
            f32x4 c0 = s0 + BSLOT(FBA0, k0, 0), c1 = s1 + BSLOT(FBA0, k0, 1);
            f32x4 c2 = s2 + BSLOT(FBA0, k0, 2), c3 = s3 + BSLOT(FBA0, k0, 3);
            c0 = MFMA(K00, p0a, c0); c1 = MFMA(K10, p0a, c1);
            c2 = MFMA(K20, p0a, c2); c3 = MFMA(K30, p0a, c3);
            c0 = MFMA(K01, p1a, c0); c1 = MFMA(K11, p1a, c1);
            c2 = MFMA(K21, p1a, c2); c3 = MFMA(K31, p1a, c3);
            PACKP(c0, c1, p0a); PACKP(c2, c3, p1a);
            f32x4 d0 = s0 + BSLOT(FBA0, k1, 0), d1 = s1 + BSLOT(FBA0, k1, 1);
            f32x4 d2 = s2 + BSLOT(FBA0, k1, 2), d3 = s3 + BSLOT(FBA0, k1, 3);
            d0 = MFMA(K00, p0b, d0); d1 = MFMA(K10, p0b, d1);
            d2 = MFMA(K20, p0b, d2); d3 = MFMA(K30, p0b, d3);
            d0 = MFMA(K01, p1b, d0); d1 = MFMA(K11, p1b, d1);
            d2 = MFMA(K21, p1b, d2); d3 = MFMA(K31, p1b, d3);
            PACKP(d0, d1, p0b); PACKP(d2, d3, p1b);
        }
        LAYER64_2(FA1, FBA1, PACKP)
        LAYER64_2(FA2, FBA2, PACKP)
        LAYER64_2(FL,  FBL,  PACKN)
        { // tails: shared FV/FC frags, both slots
            short8 AV00 = FRAG(FV, 0), AV10 = FRAG(FV, 3);
            short8 AV01 = FRAG(FV, 1), AV11 = FRAG(FV, 4);
            short8 AV02 = FRAG(FV, 2), AV12 = FRAG(FV, 5);
            short8 AC0f = FRAG(FC0, 0), AC1f = FRAG(FC1, 0);
            TAIL1(p0a, p1a, k0)
            TAIL1(p0b, p1b, k1)
        }
    }
}

// ================= pass B: mask-weighted reduction over k =================
__global__ __launch_bounds__(256) void reduce_kernel(float* __restrict__ out)
{
    const int p = blockIdx.x * 256 + threadIdx.x;
    float s0 = out[O_SIG + 0 * PP + p];
    float s1 = out[O_SIG + 1 * PP + p];
    float s2 = out[O_SIG + 2 * PP + p];
    float s3 = out[O_SIG + 3 * PP + p];
    float s4 = out[O_SIG + 4 * PP + p];
    float s5 = out[O_SIG + 5 * PP + p];
    float s6 = out[O_SIG + 6 * PP + p];
    float s7 = out[O_SIG + 7 * PP + p];
    float msum = s0 + s1 + s2 + s3 + s4 + s5 + s6 + s7;
    float inv = 1.f / (msum + 1e-5f);
    float mk2 = s0*s0 + s1*s1 + s2*s2 + s3*s3 + s4*s4 + s5*s5 + s6*s6 + s7*s7;
    out[O_SIGALL + p] = mk2 * inv;
    float a0 = 0.f, a1 = 0.f, a2 = 0.f;
#define RK(i, sv) { float wk = (sv) * inv; \
    int b_ = O_RGB + ((i) * PP + p) * 3; \
    a0 = fmaf(wk, out[b_ + 0], a0); \
    a1 = fmaf(wk, out[b_ + 1], a1); \
    a2 = fmaf(wk, out[b_ + 2], a2); }
    RK(0, s0) RK(1, s1) RK(2, s2) RK(3, s3)
    RK(4, s4) RK(5, s5) RK(6, s6) RK(7, s7)
#undef RK
    out[p * 3 + 0] = a0;
    out[p * 3 + 1] = a1;
    out[p * 3 + 2] = a2;
}

extern "C" void kernel_launch(void* const* d_in, const int* in_sizes, int n_in,
                              void* d_out, int out_size, void* d_ws, size_t ws_size,
                              hipStream_t stream) {
    const float* coor  = (const float*)d_in[0];
    const float* view  = (const float*)d_in[1];
    const float* slots = (const float*)d_in[2];
    const float* dens  = (const float*)d_in[3];
    const float* shf   = (const float*)d_in[4];
    const float* Wb0 = (const float*)d_in[5];  const float* bb0 = (const float*)d_in[6];
    const float* Wb1 = (const float*)d_in[7];  const float* bb1 = (const float*)d_in[8];
    const float* Wb2 = (const float*)d_in[9];  const float* bb2 = (const float*)d_in[10];
    const float* Wa0 = (const float*)d_in[11]; const float* ba0 = (const float*)d_in[12];
    const float* Wa1 = (const float*)d_in[13]; const float* ba1 = (const float*)d_in[14];
    const float* Wa2 = (const float*)d_in[15]; const float* ba2 = (const float*)d_in[16];
    const float* Wl  = (const float*)d_in[17]; const float* bl  = (const float*)d_in[18];
    const float* Wv  = (const float*)d_in[19]; const float* bv  = (const float*)d_in[20];
    const float* Wc0 = (const float*)d_in[21]; const float* bc0 = (const float*)d_in[22];
    const float* Wc1 = (const float*)d_in[23]; const float* bc1 = (const float*)d_in[24];
    const int*   ray = (const int*)d_in[25];
    float* out = (float*)d_out;

    prep_kernel<<<dim3(1), dim3(256), 0, stream>>>(
        slots, Wb0, bb0, Wb1, bb1, Wb2, bb2,
        Wa0, ba0, Wa1, ba1, Wa2, ba2,
        Wl, bl, Wv, bv, Wc0, bc0, Wc1, bc1, (char*)d_ws);

    decoder_kernel<<<dim3(PP / 128), dim3(512), 0, stream>>>(
        coor, view, dens, shf, ray, (const char*)d_ws, out);

    reduce_kernel<<<dim3(PP / 256), dim3(256), 0, stream>>>(out);
}

// Round 20
// 184.659 us; speedup vs baseline: 5.6434x; 5.6434x over previous
//
#include <hip/hip_runtime.h>
#include <hip/hip_bf16.h>
#include <math.h>

#define PP 196608
#define NK 8

#define O_SIGALL 589824
#define O_RGB    786432
#define O_SIG    5505024

typedef __attribute__((ext_vector_type(8))) short short8;
typedef __attribute__((ext_vector_type(4))) float f32x4;
typedef __attribute__((ext_vector_type(4))) unsigned uint4v;

// ---- f32 table offsets (floats; bytes 0..6143 of ws and LDS) ----
#define FBB0   0
#define FBA0   512
#define FBB1   1024
#define FBB2   1088
#define FBA1   1152
#define FBA2   1216
#define FBL    1280
#define FBV    1344
#define FBC0   1376
#define FBC1   1392
#define FW32B0 1408
#define FW32A0 1472
// f32 total = 1536 floats = 6144 bytes

// ---- bf16 fragment regions (shorts; 1 frag = 64 lanes x 8 shorts = 512) ----
#define FB0 0
#define FB1 2048
#define FB2 6144
#define FA0 10240
#define FA1 16384
#define FA2 20480
#define FL  24576
#define FV  28672
#define FC0 31744
#define FC1 32256
// frag total = 32768 shorts = 65536 bytes; image = 71680 bytes

#define WS_BYTES 71680

__device__ __forceinline__ short bfr(float f) {
    unsigned u = __builtin_bit_cast(unsigned, f);
    unsigned r = (u + 0x7FFFu + ((u >> 16) & 1u)) >> 16;
    return (short)r;
}

// packed pair f32 -> 2x bf16 (RNE) in one u32
__device__ __forceinline__ unsigned pk2(float a, float b) {
    __hip_bfloat162 h = __float22bfloat162_rn(float2{a, b});
    unsigned r;
    __builtin_memcpy(&r, &h, sizeof(r));
    return r;
}

__device__ __forceinline__ int tau(int p) {
    return 16 * ((p >> 2) & 1) + 4 * (p >> 3) + (p & 3);
}

__device__ __forceinline__ float pe_elem(int j, float c0, float c1, float c2, int jmax) {
    int r = j - 3;
    int rf = r < 0 ? 0 : r;
    int f = rf / 6;
    int t = rf - 6 * f;
    int comp = (j < 3) ? j : (t >= 3 ? t - 3 : t);
    float c = (comp == 0) ? c0 : ((comp == 1) ? c1 : c2);
    float x = c * (float)(1 << f);
    float val = (t < 3) ? sinf(x) : cosf(x);
    if (j < 3) val = c;
    return (j < jmax) ? val : 0.f;
}

// fast softplus: hardware exp/log (v_exp_f32 / v_log_f32), ~1e-6 rel err
__device__ __forceinline__ float softplus_(float d) {
    return fmaxf(d, 0.f) + __logf(1.f + __expf(-fabsf(d)));
}
// (tanh(x)+1)/2 == sigmoid(2x); ~4 VALU via v_exp
__device__ __forceinline__ float half_tanh1(float x) {
    return 1.f / (1.f + __expf(-2.f * x));
}

#define MFMA(a, b, c) __builtin_amdgcn_mfma_f32_16x16x32_bf16(a, b, c, 0, 0, 0)

// ================= prep kernel: frag-linear ws image (verified) =================
__global__ void prep_kernel(
    const float* __restrict__ slots,
    const float* __restrict__ Wb0, const float* __restrict__ bb0,
    const float* __restrict__ Wb1, const float* __restrict__ bb1,
    const float* __restrict__ Wb2, const float* __restrict__ bb2,
    const float* __restrict__ Wa0, const float* __restrict__ ba0,
    const float* __restrict__ Wa1, const float* __restrict__ ba1,
    const float* __restrict__ Wa2, const float* __restrict__ ba2,
    const float* __restrict__ Wl,  const float* __restrict__ bl,
    const float* __restrict__ Wv,  const float* __restrict__ bv,
    const float* __restrict__ Wc0, const float* __restrict__ bc0,
    const float* __restrict__ Wc1, const float* __restrict__ bc1,
    char* __restrict__ ws)
{
    float* wsF = (float*)ws;
    short* wsS = (short*)(ws + 6144);
    const int tid = threadIdx.x;

    for (int idx = tid; idx < 512; idx += 256) {
        int k = idx >> 6, j = idx & 63;
        const float* sl = slots + k * 64;
        float a = bb0[j];
        const float* w0 = Wb0 + j * 97 + 33;
        for (int i = 0; i < 64; ++i) a = fmaf(w0[i], sl[i], a);
        wsF[FBB0 + idx] = a;
        float b = ba0[j];
        const float* w1 = Wa0 + j * 161 + 33;
        for (int i = 0; i < 64; ++i) b = fmaf(w1[i], sl[i], b);
        wsF[FBA0 + idx] = b;
    }
    for (int idx = tid; idx < 64; idx += 256) {
        wsF[FBB1 + idx] = bb1[idx];
        wsF[FBB2 + idx] = bb2[idx];
        wsF[FBA1 + idx] = ba1[idx];
        wsF[FBA2 + idx] = ba2[idx];
        wsF[FBL  + idx] = bl[idx];
        wsF[FW32B0 + idx] = Wb0[idx * 97 + 32];
        wsF[FW32A0 + idx] = Wa0[idx * 161 + 32];
        if (idx < 32) wsF[FBV + idx] = bv[idx];
        if (idx < 16) { wsF[FBC0 + idx] = bc0[idx];
                        wsF[FBC1 + idx] = (idx < 3) ? bc1[idx] : 0.f; }
    }
    for (int idx = tid; idx < 2048; idx += 256) {
        int frag = idx >> 9, rem = idx & 511, L = rem >> 3, i = rem & 7;
        int r = 16 * frag + (L & 15);
        int cif = 8 * (L >> 4) + i;
        wsS[FB0 + idx] = bfr(Wb0[r * 97 + tau(cif)]);
    }
#define PREP64(FOFF, W) \
    for (int idx = tid; idx < 4096; idx += 256) { \
        int frag = idx >> 9, rem = idx & 511, L = rem >> 3, i = rem & 7; \
        int t = frag >> 1, s = frag & 1; \
        int r = 16 * t + (L & 15); \
        int cif = 8 * (L >> 4) + i; \
        int C = 32 * s + cif; \
        int lc = (C & ~31) + tau(C & 31); \
        wsS[(FOFF) + idx] = bfr(W[r * 64 + lc]); }
    PREP64(FB1, Wb1)
    PREP64(FB2, Wb2)
    PREP64(FA1, Wa1)
    PREP64(FA2, Wa2)
    PREP64(FL,  Wl)
#undef PREP64
    for (int idx = tid; idx < 6144; idx += 256) {
        int frag = idx >> 9, rem = idx & 511, L = rem >> 3, i = rem & 7;
        int t = frag / 3, s = frag % 3;
        int r = 16 * t + (L & 15);
        int cif = 8 * (L >> 4) + i;
        float v;
        if (s == 0) v = Wa0[r * 161 + tau(cif)];
        else {
            int lc = (s == 1 ? 64 : 96) + tau(cif);
            v = Wa0[r * 161 + 33 + lc];
        }
        wsS[FA0 + idx] = bfr(v);
    }
    for (int idx = tid; idx < 3072; idx += 256) {
        int frag = idx >> 9, rem = idx & 511, L = rem >> 3, i = rem & 7;
        int t = frag / 3, s = frag % 3;
        int r = 16 * t + (L & 15);
        int cif = 8 * (L >> 4) + i;
        int C = 32 * s + cif;
        int lc = (C & ~31) + tau(C & 31);
        wsS[FV + idx] = bfr(lc < 85 ? Wv[r * 85 + lc] : 0.f);
    }
    for (int idx = tid; idx < 512; idx += 256) {
        int L = idx >> 3, i = idx & 7;
        int r = L & 15;
        int cif = 8 * (L >> 4) + i;
        int lc = tau(cif);
        wsS[FC0 + idx] = bfr(Wc0[r * 32 + lc]);
        wsS[FC1 + idx] = bfr((r < 3 && lc < 16) ? Wc1[r * 16 + lc] : 0.f);
    }
}

// ---- LDS access (lane-linear frags: conflict-free ds_read_b128; verified) ----
#define FRAG(base, f) (*(const short8*)(shS + (base) + (f) * 512 + l * 8))
#define BIA(off, t)   (*(const f32x4*)(shF + (off) + 16 * (t) + g4))
#define BSLOT(off, kidx, t) (*(const f32x4*)(shF + (off) + (kidx) * 64 + 16 * (t) + g4))

#define PACKP(cA, cB, dst) { uint4v u_; \
  u_[0] = pk2(fmaxf((cA)[0],0.f), fmaxf((cA)[1],0.f)); \
  u_[1] = pk2(fmaxf((cA)[2],0.f), fmaxf((cA)[3],0.f)); \
  u_[2] = pk2(fmaxf((cB)[0],0.f), fmaxf((cB)[1],0.f)); \
  u_[3] = pk2(fmaxf((cB)[2],0.f), fmaxf((cB)[3],0.f)); \
  dst = __builtin_bit_cast(short8, u_); }

#define PACKN(cA, cB, dst) { uint4v u_; \
  u_[0] = pk2((cA)[0], (cA)[1]); \
  u_[1] = pk2((cA)[2], (cA)[3]); \
  u_[2] = pk2((cB)[0], (cB)[1]); \
  u_[3] = pk2((cB)[2], (cB)[3]); \
  dst = __builtin_bit_cast(short8, u_); }

#define ADD32(c, wv) { (c)[0]=fmaf((wv)[0],cosv,(c)[0]); (c)[1]=fmaf((wv)[1],cosv,(c)[1]); \
                       (c)[2]=fmaf((wv)[2],cosv,(c)[2]); (c)[3]=fmaf((wv)[3],cosv,(c)[3]); }

// 64x64 layer for SLOT PAIR: one frag-read set serves both slots.
#define LAYER64_2(FB, BOFF, PK) { \
  short8 A00=FRAG(FB,0), A01=FRAG(FB,1), A10=FRAG(FB,2), A11=FRAG(FB,3); \
  short8 A20=FRAG(FB,4), A21=FRAG(FB,5), A30=FRAG(FB,6), A31=FRAG(FB,7); \
  f32x4 b0_=BIA(BOFF,0), b1_=BIA(BOFF,1), b2_=BIA(BOFF,2), b3_=BIA(BOFF,3); \
  f32x4 c0=b0_, c1=b1_, c2=b2_, c3=b3_; \
  c0=MFMA(A00,p0a,c0); c1=MFMA(A10,p0a,c1); c2=MFMA(A20,p0a,c2); c3=MFMA(A30,p0a,c3); \
  c0=MFMA(A01,p1a,c0); c1=MFMA(A11,p1a,c1); c2=MFMA(A21,p1a,c2); c3=MFMA(A31,p1a,c3); \
  PK(c0,c1,p0a); PK(c2,c3,p1a); \
  f32x4 d0=b0_, d1=b1_, d2=b2_, d3=b3_; \
  d0=MFMA(A00,p0b,d0); d1=MFMA(A10,p0b,d1); d2=MFMA(A20,p0b,d2); d3=MFMA(A30,p0b,d3); \
  d0=MFMA(A01,p1b,d0); d1=MFMA(A11,p1b,d1); d2=MFMA(A21,p1b,d2); d3=MFMA(A31,p1b,d3); \
  PK(d0,d1,p0b); PK(d2,d3,p1b); }

// tail for one slot (AV*/AC* frags shared, loaded by caller)
#define TAIL1(PA, PB, KIDX) { \
  f32x4 cv0 = BIA(FBV, 0), cv1 = BIA(FBV, 1); \
  cv0 = MFMA(AV00, PA, cv0); cv1 = MFMA(AV10, PA, cv1); \
  cv0 = MFMA(AV01, PB, cv0); cv1 = MFMA(AV11, PB, cv1); \
  cv0 = MFMA(AV02, vembB, cv0); cv1 = MFMA(AV12, vembB, cv1); \
  short8 vB; PACKP(cv0, cv1, vB); \
  f32x4 cc = BIA(FBC0, 0); \
  cc = MFMA(AC0f, vB, cc); \
  short8 cB; \
  { uint4v u_; \
    u_[0] = pk2(fmaxf(cc[0],0.f), fmaxf(cc[1],0.f)); \
    u_[1] = pk2(fmaxf(cc[2],0.f), fmaxf(cc[3],0.f)); \
    u_[2] = 0u; u_[3] = 0u; \
    cB = __builtin_bit_cast(short8, u_); } \
  f32x4 cf = BIA(FBC1, 0); \
  cf = MFMA(AC1f, cB, cf); \
  if (l < 16) { \
      int base_ = O_RGB + ((KIDX) * PP + p) * 3; \
      out[base_ + 0] = half_tanh1(cf[0]); \
      out[base_ + 1] = half_tanh1(cf[1]); \
      out[base_ + 2] = half_tanh1(cf[2]); } }

// ================= pass A: 128 points/block (8 waves), 2 slots per iter =================
__global__ __launch_bounds__(512, 4) void decoder_kernel(
    const float* __restrict__ coor,
    const float* __restrict__ view,
    const float* __restrict__ dens,
    const float* __restrict__ act_shift,
    const int*   __restrict__ ray_id,
    const char*  __restrict__ ws,
    float* __restrict__ out)
{
    __shared__ __align__(16) char sh[WS_BYTES];
    const float* shF = (const float*)sh;
    const short* shS = (const short*)(sh + 6144);

    const int tid = threadIdx.x;
    const int l   = tid & 63;
    const int l15 = l & 15;
    const int g   = (l >> 4) & 3;
    const int g4  = g * 4;
    const int p   = blockIdx.x * 128 + (tid >> 6) * 16 + l15;

    // ---- stage weight image into LDS (one coalesced pass) ----
    {
        f32x4* dst = (f32x4*)sh;
        const f32x4* src = (const f32x4*)ws;
        for (int i = tid; i < WS_BYTES / 16; i += 512) dst[i] = src[i];
    }

    // ---- pos-emb fragment + col-32 scalar: ONCE per point ----
    short8 embB0;
    float cosv;
    {
        float c0 = coor[p * 3 + 0], c1 = coor[p * 3 + 1], c2 = coor[p * 3 + 2];
        #pragma unroll
        for (int i = 0; i < 8; ++i) {
            int j = ((i >> 2) * 16) + 4 * g + (i & 3);
            embB0[i] = bfr(pe_elem(j, c0, c1, c2, 33));
        }
        cosv = cosf(c2 * 16.f);
    }
    // ---- view embedding fragment: ONCE per point ----
    short8 vembB;
    {
        int rid = ray_id[p];
        float v0 = view[rid * 3 + 0], v1 = view[rid * 3 + 1], v2 = view[rid * 3 + 2];
        #pragma unroll
        for (int i = 0; i < 8; ++i) {
            int j = ((i >> 2) * 16) + 4 * g + (i & 3);
            vembB[i] = bfr(pe_elem(j, v0, v1, v2, 21));
        }
    }
    float shift = act_shift[0];

    __syncthreads();   // LDS image ready

    #pragma unroll 1
    for (int kk = 0; kk < 4; ++kk) {
        // REQUIRED: prevents LICM/rescheduling from hoisting invariant ds_reads
        // past the register budget (R19 removed this -> 2.2 GB scratch spill, 5x slower)
        asm volatile("" ::: "memory");

        const int k0 = 2 * kk, k1 = 2 * kk + 1;

        { // both slots' sigma
            float da = dens[k0 * PP + p] + shift;
            float sa = softplus_(da);
            if (l < 16) out[O_SIG + k0 * PP + p] = sa;
            float db = dens[k1 * PP + p] + shift;
            float sb = softplus_(db);
            if (l < 16) out[O_SIG + k1 * PP + p] = sb;
        }

        short8 p0a, p1a, p0b, p1b;

        { // b0: shared W*emb + col32, per-slot bias add
            short8 A0 = FRAG(FB0, 0), A1 = FRAG(FB0, 1), A2 = FRAG(FB0, 2), A3 = FRAG(FB0, 3);
            f32x4 wv0 = BIA(FW32B0, 0), wv1 = BIA(FW32B0, 1), wv2 = BIA(FW32B0, 2), wv3 = BIA(FW32B0, 3);
            f32x4 z = {0.f, 0.f, 0.f, 0.f};
            f32x4 t0 = MFMA(A0, embB0, z), t1 = MFMA(A1, embB0, z);
            f32x4 t2 = MFMA(A2, embB0, z), t3 = MFMA(A3, embB0, z);
            ADD32(t0, wv0) ADD32(t1, wv1) ADD32(t2, wv2) ADD32(t3, wv3)
            f32x4 c0 = t0 + BSLOT(FBB0, k0, 0), c1 = t1 + BSLOT(FBB0, k0, 1);
            f32x4 c2 = t2 + BSLOT(FBB0, k0, 2), c3 = t3 + BSLOT(FBB0, k0, 3);
            PACKP(c0, c1, p0a); PACKP(c2, c3, p1a);
            f32x4 d0 = t0 + BSLOT(FBB0, k1, 0), d1 = t1 + BSLOT(FBB0, k1, 1);
            f32x4 d2 = t2 + BSLOT(FBB0, k1, 2), d3 = t3 + BSLOT(FBB0, k1, 3);
            PACKP(d0, d1, p0b); PACKP(d2, d3, p1b);
        }
        LAYER64_2(FB1, FBB1, PACKP)
        LAYER64_2(FB2, FBB2, PACKP)
        { // a0: shared W_emb*emb + col32; per-slot bias + skip MFMAs
            short8 E0 = FRAG(FA0, 0), K00 = FRAG(FA0, 1),  K01 = FRAG(FA0, 2);
            short8 E1 = FRAG(FA0, 3), K10 = FRAG(FA0, 4),  K11 = FRAG(FA0, 5);
            short8 E2 = FRAG(FA0, 6), K20 = FRAG(FA0, 7),  K21 = FRAG(FA0, 8);
            short8 E3 = FRAG(FA0, 9), K30 = FRAG(FA0, 10), K31 = FRAG(FA0, 11);
            f32x4 wv0 = BIA(FW32A0, 0), wv1 = BIA(FW32A0, 1), wv2 = BIA(FW32A0, 2), wv3 = BIA(FW32A0, 3);
            f32x4 z = {0.f, 0.f, 0.f, 0.f};
            f32x4 s0 = MFMA(E0, embB0, z), s1 = MFMA(E1, embB0, z);
            f32x4 s2 = MFMA(E2, embB0, z), s3 = MFMA(E3, embB0, z);
            ADD32(s0, wv0) ADD32(s1, wv1) ADD32(s2, wv2) ADD32(s3, wv3)
            f32x4 c0 = s0 + BSLOT(FBA0, k0, 0), c1 = s1 + BSLOT(FBA0, k0, 1);
            f32x4 c2 = s2 + BSLOT(FBA0, k0, 2), c3 = s3 + BSLOT(FBA0, k0, 3);
            c0 = MFMA(K00, p0a, c0); c1 = MFMA(K10, p0a, c1);
            c2 = MFMA(K20, p0a, c2); c3 = MFMA(K30, p0a, c3);
            c0 = MFMA(K01, p1a, c0); c1 = MFMA(K11, p1a, c1);
            c2 = MFMA(K21, p1a, c2); c3 = MFMA(K31, p1a, c3);
            PACKP(c0, c1, p0a); PACKP(c2, c3, p1a);
            f32x4 d0 = s0 + BSLOT(FBA0, k1, 0), d1 = s1 + BSLOT(FBA0, k1, 1);
            f32x4 d2 = s2 + BSLOT(FBA0, k1, 2), d3 = s3 + BSLOT(FBA0, k1, 3);
            d0 = MFMA(K00, p0b, d0); d1 = MFMA(K10, p0b, d1);
            d2 = MFMA(K20, p0b, d2); d3 = MFMA(K30, p0b, d3);
            d0 = MFMA(K01, p1b, d0); d1 = MFMA(K11, p1b, d1);
            d2 = MFMA(K21, p1b, d2); d3 = MFMA(K31, p1b, d3);
            PACKP(d0, d1, p0b); PACKP(d2, d3, p1b);
        }
        LAYER64_2(FA1, FBA1, PACKP)
        LAYER64_2(FA2, FBA2, PACKP)
        LAYER64_2(FL,  FBL,  PACKN)
        { // tails: shared FV/FC frags, both slots
            short8 AV00 = FRAG(FV, 0), AV10 = FRAG(FV, 3);
            short8 AV01 = FRAG(FV, 1), AV11 = FRAG(FV, 4);
            short8 AV02 = FRAG(FV, 2), AV12 = FRAG(FV, 5);
            short8 AC0f = FRAG(FC0, 0), AC1f = FRAG(FC1, 0);
            TAIL1(p0a, p1a, k0)
            TAIL1(p0b, p1b, k1)
        }
    }
}

// ================= pass B: mask-weighted reduction over k =================
__global__ __launch_bounds__(256) void reduce_kernel(float* __restrict__ out)
{
    const int p = blockIdx.x * 256 + threadIdx.x;
    float s0 = out[O_SIG + 0 * PP + p];
    float s1 = out[O_SIG + 1 * PP + p];
    float s2 = out[O_SIG + 2 * PP + p];
    float s3 = out[O_SIG + 3 * PP + p];
    float s4 = out[O_SIG + 4 * PP + p];
    float s5 = out[O_SIG + 5 * PP + p];
    float s6 = out[O_SIG + 6 * PP + p];
    float s7 = out[O_SIG + 7 * PP + p];
    float msum = s0 + s1 + s2 + s3 + s4 + s5 + s6 + s7;
    float inv = 1.f / (msum + 1e-5f);
    float mk2 = s0*s0 + s1*s1 + s2*s2 + s3*s3 + s4*s4 + s5*s5 + s6*s6 + s7*s7;
    out[O_SIGALL + p] = mk2 * inv;
    float a0 = 0.f, a1 = 0.f, a2 = 0.f;
#define RK(i, sv) { float wk = (sv) * inv; \
    int b_ = O_RGB + ((i) * PP + p) * 3; \
    a0 = fmaf(wk, out[b_ + 0], a0); \
    a1 = fmaf(wk, out[b_ + 1], a1); \
    a2 = fmaf(wk, out[b_ + 2], a2); }
    RK(0, s0) RK(1, s1) RK(2, s2) RK(3, s3)
    RK(4, s4) RK(5, s5) RK(6, s6) RK(7, s7)
#undef RK
    out[p * 3 + 0] = a0;
    out[p * 3 + 1] = a1;
    out[p * 3 + 2] = a2;
}

extern "C" void kernel_launch(void* const* d_in, const int* in_sizes, int n_in,
                              void* d_out, int out_size, void* d_ws, size_t ws_size,
                              hipStream_t stream) {
    const float* coor  = (const float*)d_in[0];
    const float* view  = (const float*)d_in[1];
    const float* slots = (const float*)d_in[2];
    const float* dens  = (const float*)d_in[3];
    const float* shf   = (const float*)d_in[4];
    const float* Wb0 = (const float*)d_in[5];  const float* bb0 = (const float*)d_in[6];
    const float* Wb1 = (const float*)d_in[7];  const float* bb1 = (const float*)d_in[8];
    const float* Wb2 = (const float*)d_in[9];  const float* bb2 = (const float*)d_in[10];
    const float* Wa0 = (const float*)d_in[11]; const float* ba0 = (const float*)d_in[12];
    const float* Wa1 = (const float*)d_in[13]; const float* ba1 = (const float*)d_in[14];
    const float* Wa2 = (const float*)d_in[15]; const float* ba2 = (const float*)d_in[16];
    const float* Wl  = (const float*)d_in[17]; const float* bl  = (const float*)d_in[18];
    const float* Wv  = (const float*)d_in[19]; const float* bv  = (const float*)d_in[20];
    const float* Wc0 = (const float*)d_in[21]; const float* bc0 = (const float*)d_in[22];
    const float* Wc1 = (const float*)d_in[23]; const float* bc1 = (const float*)d_in[24];
    const int*   ray = (const int*)d_in[25];
    float* out = (float*)d_out;

    prep_kernel<<<dim3(1), dim3(256), 0, stream>>>(
        slots, Wb0, bb0, Wb1, bb1, Wb2, bb2,
        Wa0, ba0, Wa1, ba1, Wa2, ba2,
        Wl, bl, Wv, bv, Wc0, bc0, Wc1, bc1, (char*)d_ws);

    decoder_kernel<<<dim3(PP / 128), dim3(512), 0, stream>>>(
        coor, view, dens, shf, ray, (const char*)d_ws, out);

    reduce_kernel<<<dim3(PP / 256), dim3(256), 0, stream>>>(out);
}